// Round 14
// baseline (539.968 us; speedup 1.0000x reference)
//
#include <hip/hip_runtime.h>
#include <hip/hip_bf16.h>
#include <hip/hip_cooperative_groups.h>

namespace cg = cooperative_groups;

typedef __attribute__((ext_vector_type(8))) short short8;
typedef __attribute__((ext_vector_type(4))) short short4_t;
typedef __attribute__((ext_vector_type(4))) float f32x4;

// Clamp-free: IEEE inf semantics give exact limits (exp->inf => rcp->0), NaN-free.
__device__ __forceinline__ float fast_sigmoid(float x) {
    return __builtin_amdgcn_rcpf(1.f + __expf(-x));
}
__device__ __forceinline__ float fast_tanh(float x) {
    return 1.f - 2.f * __builtin_amdgcn_rcpf(1.f + __expf(2.f * x));
}
// round-to-nearest-even f32 -> bf16 bits
__device__ __forceinline__ short f2bf(float f) {
    unsigned u = __float_as_uint(f);
    return (short)((u + 0x7fff + ((u >> 16) & 1)) >> 16);
}
__device__ __forceinline__ float bf2f(short b) {
    return __uint_as_float(((unsigned)(unsigned short)b) << 16);
}
// LDS-only workgroup barrier (proven R3-R12)
__device__ __forceinline__ void bar_lds() {
    asm volatile("s_waitcnt lgkmcnt(0)\n\ts_barrier" ::: "memory");
}

// ---- shared-memory union across phases (max 33 KB) ----
struct __align__(16) GemmSh { short Abh[2][2048]; short Abl[2][2048];
                              short Bbh[2][2048]; short Bbl[2][2048]; };   // 32 KB
struct __align__(16) AttnSh { float oKT[1024]; float va2s[128]; float inv8[8];
                              float scf[6144]; };                          // ~29 KB
struct __align__(16) GruSh  { short hbuf[2][256]; float xbuf[6144];
                              float obuf[2048]; };                         // 33 KB
union __align__(16) SharedMem { GemmSh g; AttnSh a; GruSh r; };

// ---------------- MFMA GEMM tile (64x64, 512 threads = 8 waves) ----------------------
// Wave = 32m x 16n quadrant (2 MFMA tiles). A,W staged per k32 as bf16 hi/lo, parity
// double-buffer, register prefetch, ONE bar_lds per iter (R12 pipeline). 3-combo MFMA
// (AhiBhi+AloBhi+AhiBl) ~2^-16 precision. C mapping col=lane&15 (n), row=quad*4+reg (m).
// mode 1: out = sigmoid(.) * A[m,n] (requires K == N).
__device__ void gemm_tile(GemmSh& sh,
                          const float* __restrict__ A, const float* __restrict__ W,
                          const float* __restrict__ bias, float* __restrict__ out,
                          int m0, int n0, int N, int K, int mode) {
    const int tid = threadIdx.x;
    const int wave = tid >> 6, lane = tid & 63;
    const int mrow = lane & 15, quad = lane >> 4;
    const int wm = (wave >> 2) * 32, wn = (wave & 3) * 16;
    const int r_ = tid >> 3;          // 0..63 staging row
    const int sg = (tid & 7) * 4;     // k offset (4 floats)

    bar_lds();  // prior phase/job LDS reads complete before overwrite

    f32x4 acc[2];
    acc[0] = (f32x4){0.f, 0.f, 0.f, 0.f};
    acc[1] = (f32x4){0.f, 0.f, 0.f, 0.f};

    float4 a = *(const float4*)(A + (size_t)(m0 + r_) * K + sg);
    float4 w = *(const float4*)(W + (size_t)(n0 + r_) * K + sg);

    for (int k0 = 0; k0 < K; k0 += 32) {
        const int cur = (k0 >> 5) & 1;
        {   // convert + commit staged regs (vmcnt wait lands here)
            float av[4] = {a.x, a.y, a.z, a.w};
            float wv[4] = {w.x, w.y, w.z, w.w};
            short4_t ah, al, bh, bl;
#pragma unroll
            for (int j = 0; j < 4; j++) {
                short h = f2bf(av[j]); ah[j] = h; al[j] = f2bf(av[j] - bf2f(h));
                short g = f2bf(wv[j]); bh[j] = g; bl[j] = f2bf(wv[j] - bf2f(g));
            }
            *(short4_t*)&sh.Abh[cur][r_ * 32 + sg] = ah;
            *(short4_t*)&sh.Abl[cur][r_ * 32 + sg] = al;
            *(short4_t*)&sh.Bbh[cur][r_ * 32 + sg] = bh;
            *(short4_t*)&sh.Bbl[cur][r_ * 32 + sg] = bl;
        }
        if (k0 + 32 < K) {  // prefetch next k-chunk (in flight across bar_lds)
            a = *(const float4*)(A + (size_t)(m0 + r_) * K + k0 + 32 + sg);
            w = *(const float4*)(W + (size_t)(n0 + r_) * K + k0 + 32 + sg);
        }
        bar_lds();  // parity double-buffer makes one barrier per iter sufficient
        short8 Ah[2], Al[2];
#pragma unroll
        for (int mt = 0; mt < 2; mt++) {
            int ar = (wm + mt * 16 + mrow) * 32 + quad * 8;
            Ah[mt] = *(const short8*)&sh.Abh[cur][ar];
            Al[mt] = *(const short8*)&sh.Abl[cur][ar];
        }
        int br = (wn + mrow) * 32 + quad * 8;
        short8 Bh = *(const short8*)&sh.Bbh[cur][br];
        short8 Bl = *(const short8*)&sh.Bbl[cur][br];
#pragma unroll
        for (int mt = 0; mt < 2; mt++) {
            acc[mt] = __builtin_amdgcn_mfma_f32_16x16x32_bf16(Ah[mt], Bh, acc[mt], 0, 0, 0);
            acc[mt] = __builtin_amdgcn_mfma_f32_16x16x32_bf16(Al[mt], Bh, acc[mt], 0, 0, 0);
            acc[mt] = __builtin_amdgcn_mfma_f32_16x16x32_bf16(Ah[mt], Bl, acc[mt], 0, 0, 0);
        }
    }
    const int n = n0 + wn + mrow;
    const float bsv = bias[n];
#pragma unroll
    for (int mt = 0; mt < 2; mt++)
#pragma unroll
        for (int r = 0; r < 4; r++) {
            int m = m0 + wm + mt * 16 + quad * 4 + r;
            float val = acc[mt][r] + bsv;
            if (mode == 1) val = fast_sigmoid(val) * A[(size_t)m * K + n];
            out[(size_t)m * N + n] = val;
        }
}

// ---------------- Attention, 8 queries per block (R12 body) --------------------------
__device__ void attn_block(AttnSh& sh, const float* __restrict__ v,
                           const int* __restrict__ lengths,
                           const float* __restrict__ own, const float* __restrict__ comp,
                           const float* __restrict__ v_attn, float* __restrict__ inp,
                           int job) {
    const int L = 512, D = 256, H = 128;
    const int b = job >> 6;
    const int q0 = (job & 63) * 8;
    const int len = lengths[b];
    if (q0 >= len) return;  // whole q-tile unread downstream
    const int tid = threadIdx.x;
    const float K2E = 2.8853900817779268f;  // 2*log2(e)

    for (int i = tid; i < 1024; i += 512) {
        int qq = i >> 7, hh = i & 127;
        sh.oKT[hh * 8 + qq] = K2E * own[((size_t)(b * L + q0 + qq)) * H + hh];
    }
    if (tid < 128) sh.va2s[tid] = -2.f * v_attn[tid];
    __syncthreads();

    {   // scores: thread = k; no max pass (|score| <= ~18, exp2 safe; shift-invariant)
        const int k = tid;
        float acc[8];
#pragma unroll
        for (int q = 0; q < 8; q++) acc[q] = 0.f;
        if (k < len) {
            const float* cp = comp + ((size_t)(b * L + k)) * H;
            for (int h = 0; h < 128; h += 4) {
                float4 c4 = *(const float4*)(cp + h);
                const float* cv = (const float*)&c4;
#pragma unroll
                for (int j = 0; j < 4; j++) {
                    float cK = cv[j] * K2E;
                    float va = sh.va2s[h + j];
                    float4 o0 = *(const float4*)&sh.oKT[(h + j) * 8];
                    float4 o1 = *(const float4*)&sh.oKT[(h + j) * 8 + 4];
                    const float* op0 = (const float*)&o0;
                    const float* op1 = (const float*)&o1;
#pragma unroll
                    for (int q = 0; q < 4; q++) {
                        float r = __builtin_amdgcn_rcpf(1.f + exp2f(cK + op0[q]));
                        acc[q] = fmaf(va, r, acc[q]);
                    }
#pragma unroll
                    for (int q = 0; q < 4; q++) {
                        float r = __builtin_amdgcn_rcpf(1.f + exp2f(cK + op1[q]));
                        acc[4 + q] = fmaf(va, r, acc[4 + q]);
                    }
                }
            }
#pragma unroll
            for (int q = 0; q < 8; q++) acc[q] = __expf(acc[q]);
        }
        *(float4*)&sh.scf[k * 12] = *(float4*)&acc[0];
        *(float4*)&sh.scf[k * 12 + 4] = *(float4*)&acc[4];
    }
    __syncthreads();

    {   // per-q denominators: wave w handles q = w
        int w = tid >> 6, l = tid & 63;
        float s = 0.f;
#pragma unroll
        for (int kk = 0; kk < 8; kk++) s += sh.scf[(l + kk * 64) * 12 + w];
#pragma unroll
        for (int off = 1; off < 64; off <<= 1) s += __shfl_xor(s, off);
        if (l == 0) sh.inv8[w] = __builtin_amdgcn_rcpf(s);
    }
    __syncthreads();

    {   // context: thread owns dim d for 4 q's
        const int d = tid & 255;
        const int qh = tid >> 8;  // 0/1
        float c0 = 0.f, c1 = 0.f, c2 = 0.f, c3 = 0.f;
        const float* vb = v + ((size_t)b * L) * D + d;
        for (int k = 0; k < L; k += 2) {
            float v0 = vb[(size_t)k * D];
            float v1 = vb[(size_t)(k + 1) * D];
            float4 s0 = *(const float4*)&sh.scf[k * 12 + qh * 4];
            float4 s1 = *(const float4*)&sh.scf[(k + 1) * 12 + qh * 4];
            c0 += s0.x * v0 + s1.x * v1;
            c1 += s0.y * v0 + s1.y * v1;
            c2 += s0.z * v0 + s1.z * v1;
            c3 += s0.w * v0 + s1.w * v1;
        }
        float cc[4] = {c0, c1, c2, c3};
#pragma unroll
        for (int j = 0; j < 4; j++) {
            int q = q0 + qh * 4 + j;
            size_t row = ((size_t)(b * L + q)) * 512;
            inp[row + 256 + d] = cc[j] * sh.inv8[qh * 4 + j];
            inp[row + d] = v[((size_t)(b * L + q)) * D + d];
        }
    }
}

// ---------------- GRU recurrence (R12 body, operand-swapped MFMA) --------------------
__device__ void gru_seq(GruSh& sh,
                        const float* __restrict__ xp_f, const float* __restrict__ xp_b,
                        const float* __restrict__ w_hh_f, const float* __restrict__ w_hh_b,
                        const float* __restrict__ b_hh_f, const float* __restrict__ b_hh_b,
                        const int* __restrict__ lengths, float* __restrict__ out, int idx) {
    const int L = 512, H = 128;
    const int dir = idx >> 2;
    const int b = idx & 3;
    const float* xp = dir ? xp_b : xp_f;
    const float* w_hh = dir ? w_hh_b : w_hh_f;
    const float* b_hh = dir ? b_hh_b : b_hh_f;
    const int tid = threadIdx.x;
    const int wave = tid >> 6;
    const int lane = tid & 63;
    const int mrow = lane & 15;
    const int quad = lane >> 4;
    const int jj = 16 * wave + lane;  // gate dim for lanes lane<16

    short8 wb[3][4];
#pragma unroll
    for (int g = 0; g < 3; g++) {
        int row = g * 128 + 16 * wave + mrow;
#pragma unroll
        for (int kt = 0; kt < 4; kt++) {
            const float* wp = w_hh + (size_t)row * H + kt * 32 + quad * 8;
            float4 w0 = *(const float4*)(wp);
            float4 w1 = *(const float4*)(wp + 4);
            float wv[8] = {w0.x, w0.y, w0.z, w0.w, w1.x, w1.y, w1.z, w1.w};
            short8 hi8;
#pragma unroll
            for (int k = 0; k < 8; k++) hi8[k] = f2bf(wv[k]);
            wb[g][kt] = hi8;
        }
    }
    float br = 0.f, bz = 0.f, bn = 0.f, hcur = 0.f;
    if (lane < 16) {
        br = b_hh[jj];
        bz = b_hh[128 + jj];
        bn = b_hh[256 + jj];
    }

    const int len = lengths[b];
    for (int i = tid; i < (L - len) * 128; i += 512) {  // zero masked tail
        int tt = len + (i >> 7);
        int kk = i & 127;
        out[((size_t)(b * L + tt)) * 256 + dir * 128 + kk] = 0.f;
    }
    if (tid < 256) sh.hbuf[0][tid] = 0;

    const int f1 = tid + 512, f2 = tid + 1024;
    const int sA = tid / 96, jA = (tid % 96) * 4;
    const int sB = f1 / 96, jB = (f1 % 96) * 4;
    const int sC = f2 / 96, jC = (f2 % 96) * 4;

    const int nch = (len + 15) >> 4;  // len >= 256 so chunk 0 is full
    float4 r0, r1, r2;
    {
        int tA = dir ? (len - 1 - sA) : sA;
        int tB = dir ? (len - 1 - sB) : sB;
        int tC = dir ? (len - 1 - sC) : sC;
        r0 = *(const float4*)&xp[((size_t)(b * L + tA)) * 384 + jA];
        r1 = *(const float4*)&xp[((size_t)(b * L + tB)) * 384 + jB];
        r2 = *(const float4*)&xp[((size_t)(b * L + tC)) * 384 + jC];
    }
    __syncthreads();

    const int bbase = (mrow & 1) * 128 + quad * 8;  // A-frag: row0=h_hi, row1=h_lo
    int par = 0;

    for (int c = 0; c < nch; c++) {
        const int cnt = min(16, len - c * 16);
        if (sA < cnt) *(float4*)&sh.xbuf[sA * 384 + jA] = r0;
        if (sB < cnt) *(float4*)&sh.xbuf[sB * 384 + jB] = r1;
        if (sC < cnt) *(float4*)&sh.xbuf[sC * 384 + jC] = r2;
        if (c > 0) {
            int p0 = (c - 1) * 16;
            for (int i = tid; i < 16 * 128; i += 512) {
                int ss = i >> 7, kk = i & 127;
                int tt = dir ? (len - 1 - (p0 + ss)) : (p0 + ss);
                out[((size_t)(b * L + tt)) * 256 + dir * 128 + kk] = sh.obuf[i];
            }
        }
        if (c + 1 < nch) {
            int ncnt = min(16, len - (c + 1) * 16);
            int base = (c + 1) * 16;
            if (sA < ncnt) {
                int tt = dir ? (len - 1 - (base + sA)) : (base + sA);
                r0 = *(const float4*)&xp[((size_t)(b * L + tt)) * 384 + jA];
            }
            if (sB < ncnt) {
                int tt = dir ? (len - 1 - (base + sB)) : (base + sB);
                r1 = *(const float4*)&xp[((size_t)(b * L + tt)) * 384 + jB];
            }
            if (sC < ncnt) {
                int tt = dir ? (len - 1 - (base + sC)) : (base + sC);
                r2 = *(const float4*)&xp[((size_t)(b * L + tt)) * 384 + jC];
            }
        }
        bar_lds();  // xbuf visible; prev obuf reads complete
        for (int s = 0; s < cnt; s++) {
            float xr, xz, xn;
            if (lane < 16) {
                xr = sh.xbuf[s * 384 + jj];
                xz = sh.xbuf[s * 384 + 128 + jj];
                xn = sh.xbuf[s * 384 + 256 + jj];
            }
            short8 af[4];
#pragma unroll
            for (int kt = 0; kt < 4; kt++) af[kt] = *(const short8*)&sh.hbuf[par][bbase + kt * 32];
            f32x4 acc[3];
#pragma unroll
            for (int g = 0; g < 3; g++) acc[g] = (f32x4){0.f, 0.f, 0.f, 0.f};
#pragma unroll
            for (int kt = 0; kt < 4; kt++)
#pragma unroll
                for (int g = 0; g < 3; g++)
                    acc[g] = __builtin_amdgcn_mfma_f32_16x16x32_bf16(af[kt], wb[g][kt], acc[g], 0, 0, 0);
            if (lane < 16) {
                float hr = acc[0][0] + acc[0][1] + br;
                float hz = acc[1][0] + acc[1][1] + bz;
                float hh = acc[2][0] + acc[2][1] + bn;
                float r = fast_sigmoid(xr + hr);
                float z = fast_sigmoid(xz + hz);
                float n = fast_tanh(xn + r * hh);
                float hn = (1.f - z) * n + z * hcur;
                hcur = hn;
                short hb = f2bf(hn);
                sh.hbuf[par ^ 1][jj] = hb;
                sh.hbuf[par ^ 1][128 + jj] = f2bf(hn - bf2f(hb));
                sh.obuf[s * 128 + jj] = hn;
            }
            par ^= 1;
            bar_lds();  // hbuf[par] ready; single barrier per step
        }
    }
    {
        int p0 = (nch - 1) * 16;
        int pcnt = len - p0;
        for (int i = tid; i < pcnt * 128; i += 512) {
            int ss = i >> 7, kk = i & 127;
            int tt = dir ? (len - 1 - (p0 + ss)) : (p0 + ss);
            out[((size_t)(b * L + tt)) * 256 + dir * 128 + kk] = sh.obuf[i];
        }
    }
}

// ---------------- Cooperative mega-kernel: all 5 phases, 4 grid syncs ----------------
__global__ __launch_bounds__(512, 1) void mega_kernel(
    const float* v, const int* lengths,
    const float* own_W, const float* own_b,
    const float* comp_W, const float* comp_b,
    const float* v_attn,
    const float* gate_W, const float* gate_b,
    const float* w_ih_f, const float* b_ih_f,
    const float* w_hh_f, const float* b_hh_f,
    const float* w_ih_b, const float* b_ih_b,
    const float* w_hh_b, const float* b_hh_b,
    float* own, float* comp, float* inp, float* gated,
    float* xp_f, float* xp_b, float* out) {
    __shared__ SharedMem sh;
    cg::grid_group grid = cg::this_grid();
    const int blk = blockIdx.x;

    // P0: own & comp projections — 128 tile-jobs (bx 0..3, by 0..31)
    if (blk < 128) {
        int bx = blk & 3, by = blk >> 2;
        int m0 = by * 64;
        if ((m0 & 511) < lengths[m0 >> 9]) {
            if (bx < 2) gemm_tile(sh.g, v, own_W, own_b, own, m0, bx * 64, 128, 256, 0);
            else        gemm_tile(sh.g, v, comp_W, comp_b, comp, m0, (bx - 2) * 64, 128, 256, 0);
        }
    }
    grid.sync();
    // P1: attention — 256 jobs
    attn_block(sh.a, v, lengths, own, comp, v_attn, inp, blk);
    grid.sync();
    // P2: gate gemm — 256 jobs (bx 0..7, by 0..31)
    {
        int bx = blk & 7, by = blk >> 3;
        int m0 = by * 64;
        if ((m0 & 511) < lengths[m0 >> 9])
            gemm_tile(sh.g, inp, gate_W, gate_b, gated, m0, bx * 64, 512, 512, 1);
    }
    grid.sync();
    // P3: xp gemms — 384 jobs (bx 0..11, by 0..31), 128 blocks take two
    for (int j = blk; j < 384; j += 256) {
        int bx = j % 12, by = j / 12;
        int m0 = by * 64;
        if ((m0 & 511) >= lengths[m0 >> 9]) continue;
        if (bx < 6) gemm_tile(sh.g, gated, w_ih_f, b_ih_f, xp_f, m0, bx * 64, 384, 512, 0);
        else        gemm_tile(sh.g, gated, w_ih_b, b_ih_b, xp_b, m0, (bx - 6) * 64, 384, 512, 0);
    }
    grid.sync();
    // P4: GRU recurrence — blocks 0..7 (others exit; no further grid syncs)
    if (blk < 8)
        gru_seq(sh.r, xp_f, xp_b, w_hh_f, w_hh_b, b_hh_f, b_hh_b, lengths, out, blk);
}

extern "C" void kernel_launch(void* const* d_in, const int* in_sizes, int n_in,
                              void* d_out, int out_size, void* d_ws, size_t ws_size,
                              hipStream_t stream) {
    const int M = 2048, H = 128;

    const float* v      = (const float*)d_in[0];
    const int* lengths  = (const int*)d_in[1];
    const float* own_W  = (const float*)d_in[3];
    const float* own_b  = (const float*)d_in[4];
    const float* comp_W = (const float*)d_in[5];
    const float* comp_b = (const float*)d_in[6];
    const float* v_attn = (const float*)d_in[7];
    const float* gate_W = (const float*)d_in[8];
    const float* gate_b = (const float*)d_in[9];
    const float* w_ih_f = (const float*)d_in[10];
    const float* w_hh_f = (const float*)d_in[11];
    const float* b_ih_f = (const float*)d_in[12];
    const float* b_hh_f = (const float*)d_in[13];
    const float* w_ih_b = (const float*)d_in[14];
    const float* w_hh_b = (const float*)d_in[15];
    const float* b_ih_b = (const float*)d_in[16];
    const float* b_hh_b = (const float*)d_in[17];

    float* ws    = (float*)d_ws;
    float* own   = ws;                       // [2048,128]
    float* comp  = own + (size_t)M * H;      // [2048,128]
    float* inp   = comp + (size_t)M * H;     // [2048,512]
    float* gated = inp + (size_t)M * 512;    // [2048,512]
    float* xp_f  = gated + (size_t)M * 512;  // [2048,384]
    float* xp_b  = xp_f + (size_t)M * 384;   // [2048,384]
    float* outp  = (float*)d_out;            // [2048,256]

    void* kargs[] = {
        (void*)&v, (void*)&lengths,
        (void*)&own_W, (void*)&own_b, (void*)&comp_W, (void*)&comp_b,
        (void*)&v_attn, (void*)&gate_W, (void*)&gate_b,
        (void*)&w_ih_f, (void*)&b_ih_f, (void*)&w_hh_f, (void*)&b_hh_f,
        (void*)&w_ih_b, (void*)&b_ih_b, (void*)&w_hh_b, (void*)&b_hh_b,
        (void*)&own, (void*)&comp, (void*)&inp, (void*)&gated,
        (void*)&xp_f, (void*)&xp_b, (void*)&outp
    };
    hipError_t err = hipLaunchCooperativeKernel((void*)mega_kernel, dim3(256), dim3(512),
                                                kargs, 0, stream);
    (void)err;
}

// Round 15
// 384.415 us; speedup vs baseline: 1.4046x; 1.4046x over previous
//
#include <hip/hip_runtime.h>
#include <hip/hip_bf16.h>

#define NEGINF -1e30f

typedef __attribute__((ext_vector_type(8))) short short8;
typedef __attribute__((ext_vector_type(4))) float f32x4;

// Clamp-free: IEEE inf semantics give exact limits (exp->inf => rcp->0), NaN-free.
__device__ __forceinline__ float fast_sigmoid(float x) {
    return __builtin_amdgcn_rcpf(1.f + __expf(-x));
}
__device__ __forceinline__ float fast_tanh(float x) {
    return 1.f - 2.f * __builtin_amdgcn_rcpf(1.f + __expf(2.f * x));
}
// round-to-nearest-even f32 -> bf16 bits
__device__ __forceinline__ short f2bf(float f) {
    unsigned u = __float_as_uint(f);
    return (short)((u + 0x7fff + ((u >> 16) & 1)) >> 16);
}
__device__ __forceinline__ float bf2f(short b) {
    return __uint_as_float(((unsigned)(unsigned short)b) << 16);
}

// LDS-only workgroup barrier (proven R3-R12): waits lgkmcnt only; in-flight global
// loads/stores are NOT drained. Safe when all cross-thread traffic goes through LDS.
__device__ __forceinline__ void bar_lds() {
    asm volatile("s_waitcnt lgkmcnt(0)\n\ts_barrier" ::: "memory");
}

// ---------------- MFMA GEMM (R12, known-good): out = A @ W^T + bias ------------------
// 64x64 tile, 256 threads = 4 waves (wave = one 32x32 quadrant = 2x2 MFMA tiles).
// A,W staged per k32 into LDS as bf16 hi/lo (parity double-buffer, register prefetch).
// 3-combo MFMA ~2^-16 precision. C mapping col=lane&15 (n), row=quad*4+reg (m).
// Row-tiles past lengths[batch] skipped. mode 1: out = sigmoid(.)*A.
__global__ __launch_bounds__(256) void gemm_bias(
    const float* __restrict__ A,
    const float* __restrict__ W1, const float* __restrict__ b1, float* __restrict__ out1,
    const float* __restrict__ W2, const float* __restrict__ b2, float* __restrict__ out2,
    const int* __restrict__ lengths,
    int M, int N, int K, int nsplit, int mode) {
    const int m0 = blockIdx.y * 64;
    if ((m0 & 511) >= lengths[m0 >> 9]) return;  // uniform per block; rows unread
    __shared__ __align__(16) short Abh[2][2048];
    __shared__ __align__(16) short Abl[2][2048];
    __shared__ __align__(16) short Bbh[2][2048];
    __shared__ __align__(16) short Bbl[2][2048];
    const int tid = threadIdx.x;
    int bx = blockIdx.x;
    const float* W = W1; const float* bias = b1; float* out = out1;
    int n0;
    if (bx < nsplit) {
        n0 = bx * 64;
    } else {
        W = W2; bias = b2; out = out2;
        n0 = (bx - nsplit) * 64;
    }
    const int wave = tid >> 6;
    const int lane = tid & 63;
    const int mrow = lane & 15;
    const int quad = lane >> 4;
    const int wm = (wave >> 1) * 32;
    const int wn = (wave & 1) * 32;

    const int r_ = tid >> 2;
    const int sg = (tid & 3) * 8;

    f32x4 acc[2][2];
#pragma unroll
    for (int mt = 0; mt < 2; mt++)
#pragma unroll
        for (int nt = 0; nt < 2; nt++) acc[mt][nt] = (f32x4){0.f, 0.f, 0.f, 0.f};

    float4 a0 = *(const float4*)(A + (size_t)(m0 + r_) * K + sg);
    float4 a1 = *(const float4*)(A + (size_t)(m0 + r_) * K + sg + 4);
    float4 w0 = *(const float4*)(W + (size_t)(n0 + r_) * K + sg);
    float4 w1 = *(const float4*)(W + (size_t)(n0 + r_) * K + sg + 4);

    for (int k0 = 0; k0 < K; k0 += 32) {
        const int cur = (k0 >> 5) & 1;
        {
            float av[8] = {a0.x, a0.y, a0.z, a0.w, a1.x, a1.y, a1.z, a1.w};
            float wv[8] = {w0.x, w0.y, w0.z, w0.w, w1.x, w1.y, w1.z, w1.w};
            short8 ah, al, bh, bl;
#pragma unroll
            for (int j = 0; j < 8; j++) {
                short h = f2bf(av[j]); ah[j] = h; al[j] = f2bf(av[j] - bf2f(h));
                short g = f2bf(wv[j]); bh[j] = g; bl[j] = f2bf(wv[j] - bf2f(g));
            }
            *(short8*)&Abh[cur][r_ * 32 + sg] = ah;
            *(short8*)&Abl[cur][r_ * 32 + sg] = al;
            *(short8*)&Bbh[cur][r_ * 32 + sg] = bh;
            *(short8*)&Bbl[cur][r_ * 32 + sg] = bl;
        }
        if (k0 + 32 < K) {
            a0 = *(const float4*)(A + (size_t)(m0 + r_) * K + k0 + 32 + sg);
            a1 = *(const float4*)(A + (size_t)(m0 + r_) * K + k0 + 32 + sg + 4);
            w0 = *(const float4*)(W + (size_t)(n0 + r_) * K + k0 + 32 + sg);
            w1 = *(const float4*)(W + (size_t)(n0 + r_) * K + k0 + 32 + sg + 4);
        }
        bar_lds();
        short8 Ah[2], Al[2], Bh[2], Bl[2];
#pragma unroll
        for (int t = 0; t < 2; t++) {
            int ar = (wm + t * 16 + mrow) * 32 + quad * 8;
            int br = (wn + t * 16 + mrow) * 32 + quad * 8;
            Ah[t] = *(const short8*)&Abh[cur][ar];
            Al[t] = *(const short8*)&Abl[cur][ar];
            Bh[t] = *(const short8*)&Bbh[cur][br];
            Bl[t] = *(const short8*)&Bbl[cur][br];
        }
#pragma unroll
        for (int mt = 0; mt < 2; mt++)
#pragma unroll
            for (int nt = 0; nt < 2; nt++) {
                acc[mt][nt] = __builtin_amdgcn_mfma_f32_16x16x32_bf16(Ah[mt], Bh[nt], acc[mt][nt], 0, 0, 0);
                acc[mt][nt] = __builtin_amdgcn_mfma_f32_16x16x32_bf16(Al[mt], Bh[nt], acc[mt][nt], 0, 0, 0);
                acc[mt][nt] = __builtin_amdgcn_mfma_f32_16x16x32_bf16(Ah[mt], Bl[nt], acc[mt][nt], 0, 0, 0);
            }
        bar_lds();
    }
    float bsv[2];
#pragma unroll
    for (int nt = 0; nt < 2; nt++) bsv[nt] = bias[n0 + wn + nt * 16 + mrow];
#pragma unroll
    for (int mt = 0; mt < 2; mt++)
#pragma unroll
        for (int nt = 0; nt < 2; nt++) {
            int n = n0 + wn + nt * 16 + mrow;
#pragma unroll
            for (int r = 0; r < 4; r++) {
                int m = m0 + wm + mt * 16 + quad * 4 + r;
                float val = acc[mt][nt][r] + bsv[nt];
                if (mode == 1) val = fast_sigmoid(val) * A[(size_t)m * K + n];
                out[(size_t)m * N + n] = val;
            }
        }
}

// ---------------- Attention, 8 queries per block (R12, known-good) -------------------
__global__ __launch_bounds__(512) void attn_kernel(
    const float* __restrict__ v, const int* __restrict__ lengths,
    const float* __restrict__ own, const float* __restrict__ comp,
    const float* __restrict__ v_attn, float* __restrict__ inp) {
    const int L = 512, D = 256, H = 128;
    const int b = blockIdx.x >> 6;
    const int q0 = (blockIdx.x & 63) * 8;
    const int len = lengths[b];
    if (q0 >= len) return;
    const int tid = threadIdx.x;
    const float K2E = 2.8853900817779268f;  // 2*log2(e)
    __shared__ __align__(16) float oKT[128 * 8];
    __shared__ float va2s[128];
    __shared__ __align__(16) float scf[512 * 12];
    __shared__ float inv8[8];

    for (int i = tid; i < 1024; i += 512) {
        int qq = i >> 7, hh = i & 127;
        oKT[hh * 8 + qq] = K2E * own[((size_t)(b * L + q0 + qq)) * H + hh];
    }
    if (tid < 128) va2s[tid] = -2.f * v_attn[tid];
    __syncthreads();

    {
        const int k = tid;
        float acc[8];
#pragma unroll
        for (int q = 0; q < 8; q++) acc[q] = 0.f;
        if (k < len) {
            const float* cp = comp + ((size_t)(b * L + k)) * H;
            for (int h = 0; h < 128; h += 4) {
                float4 c4 = *(const float4*)(cp + h);
                const float* cv = (const float*)&c4;
#pragma unroll
                for (int j = 0; j < 4; j++) {
                    float cK = cv[j] * K2E;
                    float va = va2s[h + j];
                    float4 o0 = *(const float4*)&oKT[(h + j) * 8];
                    float4 o1 = *(const float4*)&oKT[(h + j) * 8 + 4];
                    const float* op0 = (const float*)&o0;
                    const float* op1 = (const float*)&o1;
#pragma unroll
                    for (int q = 0; q < 4; q++) {
                        float r = __builtin_amdgcn_rcpf(1.f + exp2f(cK + op0[q]));
                        acc[q] = fmaf(va, r, acc[q]);
                    }
#pragma unroll
                    for (int q = 0; q < 4; q++) {
                        float r = __builtin_amdgcn_rcpf(1.f + exp2f(cK + op1[q]));
                        acc[4 + q] = fmaf(va, r, acc[4 + q]);
                    }
                }
            }
#pragma unroll
            for (int q = 0; q < 8; q++) acc[q] = __expf(acc[q]);  // bounded, no max pass
        }
        *(float4*)&scf[k * 12] = *(float4*)&acc[0];
        *(float4*)&scf[k * 12 + 4] = *(float4*)&acc[4];
    }
    __syncthreads();

    {
        int w = tid >> 6, l = tid & 63;
        float s = 0.f;
#pragma unroll
        for (int kk = 0; kk < 8; kk++) s += scf[(l + kk * 64) * 12 + w];
#pragma unroll
        for (int off = 1; off < 64; off <<= 1) s += __shfl_xor(s, off);
        if (l == 0) inv8[w] = __builtin_amdgcn_rcpf(s);
    }
    __syncthreads();

    {
        const int d = tid & 255;
        const int qh = tid >> 8;
        float c0 = 0.f, c1 = 0.f, c2 = 0.f, c3 = 0.f;
        const float* vb = v + ((size_t)b * L) * D + d;
        for (int k = 0; k < L; k += 2) {
            float v0 = vb[(size_t)k * D];
            float v1 = vb[(size_t)(k + 1) * D];
            float4 s0 = *(const float4*)&scf[k * 12 + qh * 4];
            float4 s1 = *(const float4*)&scf[(k + 1) * 12 + qh * 4];
            c0 += s0.x * v0 + s1.x * v1;
            c1 += s0.y * v0 + s1.y * v1;
            c2 += s0.z * v0 + s1.z * v1;
            c3 += s0.w * v0 + s1.w * v1;
        }
        float cc[4] = {c0, c1, c2, c3};
#pragma unroll
        for (int j = 0; j < 4; j++) {
            int q = q0 + qh * 4 + j;
            size_t row = ((size_t)(b * L + q)) * 512;
            inp[row + 256 + d] = cc[j] * inv8[qh * 4 + j];
            inp[row + d] = v[((size_t)(b * L + q)) * D + d];
        }
    }
}

// ---------------- GRU recurrence: hbuf-only LDS, register xp chunks ------------------
// One block per (dir, batch), 512 threads = 8 waves. Operand-swapped MFMA (R8-proven):
// h = A operand (row0 = h_hi, row1 = h_lo), W^T = B; hp triplet lands in gate lane's
// own acc regs. Step-loop LDS = hbuf ONLY: xp lives in gate-lane registers (48/chunk,
// fully-unrolled body; next chunk prefetched into a second register set at chunk top,
// in flight across bar_lds for a full chunk); out stores fire-and-forget per step.
// hbuf lo segment at short offset 160 (word 80 === 16 mod 32): hi/lo b128 A-frag reads
// hit disjoint 16-bank halves -> all 32 banks active per read.
__global__ __launch_bounds__(512, 1) void gru_kernel(
    const float* __restrict__ xp_f, const float* __restrict__ xp_b,
    const float* __restrict__ w_hh_f, const float* __restrict__ w_hh_b,
    const float* __restrict__ b_hh_f, const float* __restrict__ b_hh_b,
    const int* __restrict__ lengths, float* __restrict__ out) {
    const int L = 512, H = 128;
    const int dir = blockIdx.x >> 2;
    const int b = blockIdx.x & 3;
    const float* xp = dir ? xp_b : xp_f;
    const float* w_hh = dir ? w_hh_b : w_hh_f;
    const float* b_hh = dir ? b_hh_b : b_hh_f;
    const int tid = threadIdx.x;
    const int wave = tid >> 6;
    const int lane = tid & 63;
    const int mrow = lane & 15;
    const int quad = lane >> 4;
    const int jj = 16 * wave + lane;  // gate dim for lanes lane<16

    // [parity][ h_hi: 0..127 | pad | h_lo: 160..287 | pad..319 ]
    __shared__ __align__(16) short hbuf[2][320];

    // B-fragments (weights): wave w, gate g, B[k][n] = W_hh[g*128+16w+n][k]
    short8 wb[3][4];
#pragma unroll
    for (int g = 0; g < 3; g++) {
        int row = g * 128 + 16 * wave + mrow;
#pragma unroll
        for (int kt = 0; kt < 4; kt++) {
            const float* wp = w_hh + (size_t)row * H + kt * 32 + quad * 8;
            float4 w0 = *(const float4*)(wp);
            float4 w1 = *(const float4*)(wp + 4);
            float wv[8] = {w0.x, w0.y, w0.z, w0.w, w1.x, w1.y, w1.z, w1.w};
            short8 hi8;
#pragma unroll
            for (int k = 0; k < 8; k++) hi8[k] = f2bf(wv[k]);
            wb[g][kt] = hi8;
        }
    }
    float br = 0.f, bz = 0.f, bn = 0.f, hcur = 0.f;
    if (lane < 16) {
        br = b_hh[jj];
        bz = b_hh[128 + jj];
        bn = b_hh[256 + jj];
    }

    const int len = lengths[b];
    // pre-zero masked tail: out[b, t, dir*128+k] = 0 for t in [len, L)
    for (int i = tid; i < (L - len) * 128; i += 512) {
        int tt = len + (i >> 7);
        int kk = i & 127;
        out[((size_t)(b * L + tt)) * 256 + dir * 128 + kk] = 0.f;
    }
    if (tid < 320) hbuf[0][tid] = 0;

    const int nch = (len + 15) >> 4;
    // gate-lane xp registers for the current chunk (fully unrolled => stays in VGPRs)
    float xr[16], xz[16], xn[16];
    if (lane < 16) {
#pragma unroll
        for (int s = 0; s < 16; s++) {
            if (s < len) {
                int t = dir ? (len - 1 - s) : s;
                size_t base = ((size_t)(b * L + t)) * 384;
                xr[s] = xp[base + jj];
                xz[s] = xp[base + 128 + jj];
                xn[s] = xp[base + 256 + jj];
            }
        }
    }
    __syncthreads();

    const int bbase = ((mrow & 1) ? 160 : 0) + quad * 8;  // A-frag: row0=hi, row1=lo
    int par = 0;

    for (int c = 0; c < nch; c++) {
        const int cnt = min(16, len - c * 16);
        // prefetch chunk c+1 into a second register set; drains over this chunk
        float nxr[16], nxz[16], nxn[16];
        if (lane < 16 && c + 1 < nch) {
#pragma unroll
            for (int s = 0; s < 16; s++) {
                int rr = (c + 1) * 16 + s;
                if (rr < len) {
                    int t = dir ? (len - 1 - rr) : rr;
                    size_t base = ((size_t)(b * L + t)) * 384;
                    nxr[s] = xp[base + jj];
                    nxz[s] = xp[base + 128 + jj];
                    nxn[s] = xp[base + 256 + jj];
                }
            }
        }
#pragma unroll
        for (int s = 0; s < 16; s++) {
            if (s < cnt) {  // cnt uniform per block -> barrier counts match
                short8 af[4];
#pragma unroll
                for (int kt = 0; kt < 4; kt++)
                    af[kt] = *(const short8*)&hbuf[par][bbase + kt * 32];
                f32x4 acc[3];
#pragma unroll
                for (int g = 0; g < 3; g++) acc[g] = (f32x4){0.f, 0.f, 0.f, 0.f};
#pragma unroll
                for (int kt = 0; kt < 4; kt++)
#pragma unroll
                    for (int g = 0; g < 3; g++)
                        acc[g] = __builtin_amdgcn_mfma_f32_16x16x32_bf16(af[kt], wb[g][kt], acc[g], 0, 0, 0);
                // C col = lane (lanes 0-15 = this wave's gate dims); regs 0/1 = W.h_hi/W.h_lo
                if (lane < 16) {
                    float hr = acc[0][0] + acc[0][1] + br;
                    float hz = acc[1][0] + acc[1][1] + bz;
                    float hh = acc[2][0] + acc[2][1] + bn;
                    float r = fast_sigmoid(xr[s] + hr);
                    float z = fast_sigmoid(xz[s] + hz);
                    float n = fast_tanh(xn[s] + r * hh);
                    float hn = (1.f - z) * n + z * hcur;
                    hcur = hn;
                    short hb = f2bf(hn);
                    hbuf[par ^ 1][jj] = hb;
                    hbuf[par ^ 1][160 + jj] = f2bf(hn - bf2f(hb));
                    int t = dir ? (len - 1 - (c * 16 + s)) : (c * 16 + s);
                    out[((size_t)(b * L + t)) * 256 + dir * 128 + jj] = hn;  // fire-and-forget
                }
                par ^= 1;
                bar_lds();  // hbuf[par] ready; single barrier per step; vmcnt untouched
            }
        }
        // rotate prefetched chunk into place (vmcnt wait lands here, a full chunk later)
        if (lane < 16 && c + 1 < nch) {
#pragma unroll
            for (int s = 0; s < 16; s++) { xr[s] = nxr[s]; xz[s] = nxz[s]; xn[s] = nxn[s]; }
        }
    }
}

extern "C" void kernel_launch(void* const* d_in, const int* in_sizes, int n_in,
                              void* d_out, int out_size, void* d_ws, size_t ws_size,
                              hipStream_t stream) {
    const int B = 4, L = 512, D = 256, H = 128;
    const int M = B * L;  // 2048

    const float* v      = (const float*)d_in[0];
    const int* lengths  = (const int*)d_in[1];
    const float* own_W  = (const float*)d_in[3];
    const float* own_b  = (const float*)d_in[4];
    const float* comp_W = (const float*)d_in[5];
    const float* comp_b = (const float*)d_in[6];
    const float* v_attn = (const float*)d_in[7];
    const float* gate_W = (const float*)d_in[8];
    const float* gate_b = (const float*)d_in[9];
    const float* w_ih_f = (const float*)d_in[10];
    const float* w_hh_f = (const float*)d_in[11];
    const float* b_ih_f = (const float*)d_in[12];
    const float* b_hh_f = (const float*)d_in[13];
    const float* w_ih_b = (const float*)d_in[14];
    const float* w_hh_b = (const float*)d_in[15];
    const float* b_ih_b = (const float*)d_in[16];
    const float* b_hh_b = (const float*)d_in[17];

    float* ws   = (float*)d_ws;
    float* own  = ws;                       // [2048,128]
    float* comp = own + (size_t)M * H;      // [2048,128]
    float* inp  = comp + (size_t)M * H;     // [2048,512]
    float* gated = inp + (size_t)M * 512;   // [2048,512]
    float* xp_f = gated + (size_t)M * 512;  // [2048,384]
    float* xp_b = xp_f + (size_t)M * 384;   // [2048,384]
    float* out  = (float*)d_out;            // [2048,256]

    // 1: own & comp projections in one launch (tiles 0..1 -> own, 2..3 -> comp)
    gemm_bias<<<dim3(4, M / 64), 256, 0, stream>>>(
        v, own_W, own_b, own, comp_W, comp_b, comp, lengths, M, H, D, 2, 0);
    // 2: attention (8 q per block) -> inp = [v, C]
    attn_kernel<<<dim3(B * 64), 512, 0, stream>>>(v, lengths, own, comp, v_attn, inp);
    // 3: gate
    gemm_bias<<<dim3(8, M / 64), 256, 0, stream>>>(
        inp, gate_W, gate_b, gated, gate_W, gate_b, gated, lengths, M, 512, 512, 8, 1);
    // 4: input projections for both GRU directions in one launch
    gemm_bias<<<dim3(12, M / 64), 256, 0, stream>>>(
        gated, w_ih_f, b_ih_f, xp_f, w_ih_b, b_ih_b, xp_b, lengths, M, 384, 512, 6, 0);
    // 5: sequential GRU, one block per (dir, batch)
    gru_kernel<<<dim3(8), 512, 0, stream>>>(xp_f, xp_b, w_hh_f, w_hh_b, b_hh_f, b_hh_b, lengths, out);
}

// Round 16
// 376.821 us; speedup vs baseline: 1.4330x; 1.0202x over previous
//
#include <hip/hip_runtime.h>
#include <hip/hip_bf16.h>

#define NEGINF -1e30f

typedef __attribute__((ext_vector_type(8))) short short8;
typedef __attribute__((ext_vector_type(4))) float f32x4;

// Clamp-free: IEEE inf semantics give exact limits (exp->inf => rcp->0), NaN-free.
__device__ __forceinline__ float fast_sigmoid(float x) {
    return __builtin_amdgcn_rcpf(1.f + __expf(-x));
}
__device__ __forceinline__ float fast_tanh(float x) {
    return 1.f - 2.f * __builtin_amdgcn_rcpf(1.f + __expf(2.f * x));
}
// round-to-nearest-even f32 -> bf16 bits
__device__ __forceinline__ short f2bf(float f) {
    unsigned u = __float_as_uint(f);
    return (short)((u + 0x7fff + ((u >> 16) & 1)) >> 16);
}
__device__ __forceinline__ float bf2f(short b) {
    return __uint_as_float(((unsigned)(unsigned short)b) << 16);
}

// LDS-only workgroup barrier (proven R3-R15): waits lgkmcnt only; in-flight global
// loads/stores are NOT drained. Safe when all cross-thread traffic goes through LDS.
__device__ __forceinline__ void bar_lds() {
    asm volatile("s_waitcnt lgkmcnt(0)\n\ts_barrier" ::: "memory");
}

// ---------------- MFMA GEMM (R12, known-good): out = A @ W^T + bias ------------------
// 64x64 tile, 256 threads = 4 waves (wave = one 32x32 quadrant = 2x2 MFMA tiles).
// A,W staged per k32 into LDS as bf16 hi/lo (parity double-buffer, register prefetch).
// 3-combo MFMA ~2^-16 precision. C mapping col=lane&15 (n), row=quad*4+reg (m).
// Row-tiles past lengths[batch] skipped. mode 1: out = sigmoid(.)*A.
__global__ __launch_bounds__(256) void gemm_bias(
    const float* __restrict__ A,
    const float* __restrict__ W1, const float* __restrict__ b1, float* __restrict__ out1,
    const float* __restrict__ W2, const float* __restrict__ b2, float* __restrict__ out2,
    const int* __restrict__ lengths,
    int M, int N, int K, int nsplit, int mode) {
    const int m0 = blockIdx.y * 64;
    if ((m0 & 511) >= lengths[m0 >> 9]) return;  // uniform per block; rows unread
    __shared__ __align__(16) short Abh[2][2048];
    __shared__ __align__(16) short Abl[2][2048];
    __shared__ __align__(16) short Bbh[2][2048];
    __shared__ __align__(16) short Bbl[2][2048];
    const int tid = threadIdx.x;
    int bx = blockIdx.x;
    const float* W = W1; const float* bias = b1; float* out = out1;
    int n0;
    if (bx < nsplit) {
        n0 = bx * 64;
    } else {
        W = W2; bias = b2; out = out2;
        n0 = (bx - nsplit) * 64;
    }
    const int wave = tid >> 6;
    const int lane = tid & 63;
    const int mrow = lane & 15;
    const int quad = lane >> 4;
    const int wm = (wave >> 1) * 32;
    const int wn = (wave & 1) * 32;

    const int r_ = tid >> 2;
    const int sg = (tid & 3) * 8;

    f32x4 acc[2][2];
#pragma unroll
    for (int mt = 0; mt < 2; mt++)
#pragma unroll
        for (int nt = 0; nt < 2; nt++) acc[mt][nt] = (f32x4){0.f, 0.f, 0.f, 0.f};

    float4 a0 = *(const float4*)(A + (size_t)(m0 + r_) * K + sg);
    float4 a1 = *(const float4*)(A + (size_t)(m0 + r_) * K + sg + 4);
    float4 w0 = *(const float4*)(W + (size_t)(n0 + r_) * K + sg);
    float4 w1 = *(const float4*)(W + (size_t)(n0 + r_) * K + sg + 4);

    for (int k0 = 0; k0 < K; k0 += 32) {
        const int cur = (k0 >> 5) & 1;
        {
            float av[8] = {a0.x, a0.y, a0.z, a0.w, a1.x, a1.y, a1.z, a1.w};
            float wv[8] = {w0.x, w0.y, w0.z, w0.w, w1.x, w1.y, w1.z, w1.w};
            short8 ah, al, bh, bl;
#pragma unroll
            for (int j = 0; j < 8; j++) {
                short h = f2bf(av[j]); ah[j] = h; al[j] = f2bf(av[j] - bf2f(h));
                short g = f2bf(wv[j]); bh[j] = g; bl[j] = f2bf(wv[j] - bf2f(g));
            }
            *(short8*)&Abh[cur][r_ * 32 + sg] = ah;
            *(short8*)&Abl[cur][r_ * 32 + sg] = al;
            *(short8*)&Bbh[cur][r_ * 32 + sg] = bh;
            *(short8*)&Bbl[cur][r_ * 32 + sg] = bl;
        }
        if (k0 + 32 < K) {
            a0 = *(const float4*)(A + (size_t)(m0 + r_) * K + k0 + 32 + sg);
            a1 = *(const float4*)(A + (size_t)(m0 + r_) * K + k0 + 32 + sg + 4);
            w0 = *(const float4*)(W + (size_t)(n0 + r_) * K + k0 + 32 + sg);
            w1 = *(const float4*)(W + (size_t)(n0 + r_) * K + k0 + 32 + sg + 4);
        }
        bar_lds();
        short8 Ah[2], Al[2], Bh[2], Bl[2];
#pragma unroll
        for (int t = 0; t < 2; t++) {
            int ar = (wm + t * 16 + mrow) * 32 + quad * 8;
            int br = (wn + t * 16 + mrow) * 32 + quad * 8;
            Ah[t] = *(const short8*)&Abh[cur][ar];
            Al[t] = *(const short8*)&Abl[cur][ar];
            Bh[t] = *(const short8*)&Bbh[cur][br];
            Bl[t] = *(const short8*)&Bbl[cur][br];
        }
#pragma unroll
        for (int mt = 0; mt < 2; mt++)
#pragma unroll
            for (int nt = 0; nt < 2; nt++) {
                acc[mt][nt] = __builtin_amdgcn_mfma_f32_16x16x32_bf16(Ah[mt], Bh[nt], acc[mt][nt], 0, 0, 0);
                acc[mt][nt] = __builtin_amdgcn_mfma_f32_16x16x32_bf16(Al[mt], Bh[nt], acc[mt][nt], 0, 0, 0);
                acc[mt][nt] = __builtin_amdgcn_mfma_f32_16x16x32_bf16(Ah[mt], Bl[nt], acc[mt][nt], 0, 0, 0);
            }
        bar_lds();
    }
    float bsv[2];
#pragma unroll
    for (int nt = 0; nt < 2; nt++) bsv[nt] = bias[n0 + wn + nt * 16 + mrow];
#pragma unroll
    for (int mt = 0; mt < 2; mt++)
#pragma unroll
        for (int nt = 0; nt < 2; nt++) {
            int n = n0 + wn + nt * 16 + mrow;
#pragma unroll
            for (int r = 0; r < 4; r++) {
                int m = m0 + wm + mt * 16 + quad * 4 + r;
                float val = acc[mt][nt][r] + bsv[nt];
                if (mode == 1) val = fast_sigmoid(val) * A[(size_t)m * K + n];
                out[(size_t)m * N + n] = val;
            }
        }
}

// ---------------- Attention, 8 queries per block (R12, known-good) -------------------
__global__ __launch_bounds__(512) void attn_kernel(
    const float* __restrict__ v, const int* __restrict__ lengths,
    const float* __restrict__ own, const float* __restrict__ comp,
    const float* __restrict__ v_attn, float* __restrict__ inp) {
    const int L = 512, D = 256, H = 128;
    const int b = blockIdx.x >> 6;
    const int q0 = (blockIdx.x & 63) * 8;
    const int len = lengths[b];
    if (q0 >= len) return;
    const int tid = threadIdx.x;
    const float K2E = 2.8853900817779268f;  // 2*log2(e)
    __shared__ __align__(16) float oKT[128 * 8];
    __shared__ float va2s[128];
    __shared__ __align__(16) float scf[512 * 12];
    __shared__ float inv8[8];

    for (int i = tid; i < 1024; i += 512) {
        int qq = i >> 7, hh = i & 127;
        oKT[hh * 8 + qq] = K2E * own[((size_t)(b * L + q0 + qq)) * H + hh];
    }
    if (tid < 128) va2s[tid] = -2.f * v_attn[tid];
    __syncthreads();

    {
        const int k = tid;
        float acc[8];
#pragma unroll
        for (int q = 0; q < 8; q++) acc[q] = 0.f;
        if (k < len) {
            const float* cp = comp + ((size_t)(b * L + k)) * H;
            for (int h = 0; h < 128; h += 4) {
                float4 c4 = *(const float4*)(cp + h);
                const float* cv = (const float*)&c4;
#pragma unroll
                for (int j = 0; j < 4; j++) {
                    float cK = cv[j] * K2E;
                    float va = va2s[h + j];
                    float4 o0 = *(const float4*)&oKT[(h + j) * 8];
                    float4 o1 = *(const float4*)&oKT[(h + j) * 8 + 4];
                    const float* op0 = (const float*)&o0;
                    const float* op1 = (const float*)&o1;
#pragma unroll
                    for (int q = 0; q < 4; q++) {
                        float r = __builtin_amdgcn_rcpf(1.f + exp2f(cK + op0[q]));
                        acc[q] = fmaf(va, r, acc[q]);
                    }
#pragma unroll
                    for (int q = 0; q < 4; q++) {
                        float r = __builtin_amdgcn_rcpf(1.f + exp2f(cK + op1[q]));
                        acc[4 + q] = fmaf(va, r, acc[4 + q]);
                    }
                }
            }
#pragma unroll
            for (int q = 0; q < 8; q++) acc[q] = __expf(acc[q]);  // bounded, no max pass
        }
        *(float4*)&scf[k * 12] = *(float4*)&acc[0];
        *(float4*)&scf[k * 12 + 4] = *(float4*)&acc[4];
    }
    __syncthreads();

    {
        int w = tid >> 6, l = tid & 63;
        float s = 0.f;
#pragma unroll
        for (int kk = 0; kk < 8; kk++) s += scf[(l + kk * 64) * 12 + w];
#pragma unroll
        for (int off = 1; off < 64; off <<= 1) s += __shfl_xor(s, off);
        if (l == 0) inv8[w] = __builtin_amdgcn_rcpf(s);
    }
    __syncthreads();

    {
        const int d = tid & 255;
        const int qh = tid >> 8;
        float c0 = 0.f, c1 = 0.f, c2 = 0.f, c3 = 0.f;
        const float* vb = v + ((size_t)b * L) * D + d;
        for (int k = 0; k < L; k += 2) {
            float v0 = vb[(size_t)k * D];
            float v1 = vb[(size_t)(k + 1) * D];
            float4 s0 = *(const float4*)&scf[k * 12 + qh * 4];
            float4 s1 = *(const float4*)&scf[(k + 1) * 12 + qh * 4];
            c0 += s0.x * v0 + s1.x * v1;
            c1 += s0.y * v0 + s1.y * v1;
            c2 += s0.z * v0 + s1.z * v1;
            c3 += s0.w * v0 + s1.w * v1;
        }
        float cc[4] = {c0, c1, c2, c3};
#pragma unroll
        for (int j = 0; j < 4; j++) {
            int q = q0 + qh * 4 + j;
            size_t row = ((size_t)(b * L + q)) * 512;
            inp[row + 256 + d] = cc[j] * inv8[qh * 4 + j];
            inp[row + d] = v[((size_t)(b * L + q)) * D + d];
        }
    }
}

// ---------------- GRU recurrence: hbuf-only LDS, g-major MFMA + early gates ----------
// R15 structure (hbuf-only step loop, register xp chunks, fire-and-forget out,
// bank-split hi/lo at offset 160). NEW: MFMAs issue g-major (acc0 done after 4,
// acc1 after 8), and r/z sigmoid chains are written to depend only on acc0/acc1 —
// the transcendental VALU work overlaps the final 4 MFMAs (MFMA/VALU co-issue, m114).
__global__ __launch_bounds__(512, 1) void gru_kernel(
    const float* __restrict__ xp_f, const float* __restrict__ xp_b,
    const float* __restrict__ w_hh_f, const float* __restrict__ w_hh_b,
    const float* __restrict__ b_hh_f, const float* __restrict__ b_hh_b,
    const int* __restrict__ lengths, float* __restrict__ out) {
    const int L = 512, H = 128;
    const int dir = blockIdx.x >> 2;
    const int b = blockIdx.x & 3;
    const float* xp = dir ? xp_b : xp_f;
    const float* w_hh = dir ? w_hh_b : w_hh_f;
    const float* b_hh = dir ? b_hh_b : b_hh_f;
    const int tid = threadIdx.x;
    const int wave = tid >> 6;
    const int lane = tid & 63;
    const int mrow = lane & 15;
    const int quad = lane >> 4;
    const int jj = 16 * wave + lane;  // gate dim for lanes lane<16

    // [parity][ h_hi: 0..127 | pad | h_lo: 160..287 | pad..319 ]
    __shared__ __align__(16) short hbuf[2][320];

    // B-fragments (weights): wave w, gate g, B[k][n] = W_hh[g*128+16w+n][k]
    short8 wb[3][4];
#pragma unroll
    for (int g = 0; g < 3; g++) {
        int row = g * 128 + 16 * wave + mrow;
#pragma unroll
        for (int kt = 0; kt < 4; kt++) {
            const float* wp = w_hh + (size_t)row * H + kt * 32 + quad * 8;
            float4 w0 = *(const float4*)(wp);
            float4 w1 = *(const float4*)(wp + 4);
            float wv[8] = {w0.x, w0.y, w0.z, w0.w, w1.x, w1.y, w1.z, w1.w};
            short8 hi8;
#pragma unroll
            for (int k = 0; k < 8; k++) hi8[k] = f2bf(wv[k]);
            wb[g][kt] = hi8;
        }
    }
    float br = 0.f, bz = 0.f, bn = 0.f, hcur = 0.f;
    if (lane < 16) {
        br = b_hh[jj];
        bz = b_hh[128 + jj];
        bn = b_hh[256 + jj];
    }

    const int len = lengths[b];
    // pre-zero masked tail: out[b, t, dir*128+k] = 0 for t in [len, L)
    for (int i = tid; i < (L - len) * 128; i += 512) {
        int tt = len + (i >> 7);
        int kk = i & 127;
        out[((size_t)(b * L + tt)) * 256 + dir * 128 + kk] = 0.f;
    }
    if (tid < 320) hbuf[0][tid] = 0;

    const int nch = (len + 15) >> 4;
    // gate-lane xp registers for the current chunk (fully unrolled => stays in VGPRs)
    float xr[16], xz[16], xn[16];
    if (lane < 16) {
#pragma unroll
        for (int s = 0; s < 16; s++) {
            if (s < len) {
                int t = dir ? (len - 1 - s) : s;
                size_t base = ((size_t)(b * L + t)) * 384;
                xr[s] = xp[base + jj];
                xz[s] = xp[base + 128 + jj];
                xn[s] = xp[base + 256 + jj];
            }
        }
    }
    __syncthreads();

    const int bbase = ((mrow & 1) ? 160 : 0) + quad * 8;  // A-frag: row0=hi, row1=lo
    int par = 0;

    for (int c = 0; c < nch; c++) {
        const int cnt = min(16, len - c * 16);
        // prefetch chunk c+1 into a second register set; drains over this chunk
        float nxr[16], nxz[16], nxn[16];
        if (lane < 16 && c + 1 < nch) {
#pragma unroll
            for (int s = 0; s < 16; s++) {
                int rr = (c + 1) * 16 + s;
                if (rr < len) {
                    int t = dir ? (len - 1 - rr) : rr;
                    size_t base = ((size_t)(b * L + t)) * 384;
                    nxr[s] = xp[base + jj];
                    nxz[s] = xp[base + 128 + jj];
                    nxn[s] = xp[base + 256 + jj];
                }
            }
        }
#pragma unroll
        for (int s = 0; s < 16; s++) {
            if (s < cnt) {  // cnt uniform per block -> barrier counts match
                short8 af[4];
#pragma unroll
                for (int kt = 0; kt < 4; kt++)
                    af[kt] = *(const short8*)&hbuf[par][bbase + kt * 32];
                f32x4 acc0 = (f32x4){0.f, 0.f, 0.f, 0.f};
                f32x4 acc1 = (f32x4){0.f, 0.f, 0.f, 0.f};
                f32x4 acc2 = (f32x4){0.f, 0.f, 0.f, 0.f};
                // g-major: acc0 complete after 4 insts, acc1 after 8, acc2 last
#pragma unroll
                for (int kt = 0; kt < 4; kt++)
                    acc0 = __builtin_amdgcn_mfma_f32_16x16x32_bf16(af[kt], wb[0][kt], acc0, 0, 0, 0);
#pragma unroll
                for (int kt = 0; kt < 4; kt++)
                    acc1 = __builtin_amdgcn_mfma_f32_16x16x32_bf16(af[kt], wb[1][kt], acc1, 0, 0, 0);
#pragma unroll
                for (int kt = 0; kt < 4; kt++)
                    acc2 = __builtin_amdgcn_mfma_f32_16x16x32_bf16(af[kt], wb[2][kt], acc2, 0, 0, 0);
                if (lane < 16) {
                    // r,z depend only on acc0/acc1: their exp/rcp chains overlap
                    // acc2's in-flight MFMAs (separate pipes)
                    float r = fast_sigmoid(xr[s] + acc0[0] + acc0[1] + br);
                    float z = fast_sigmoid(xz[s] + acc1[0] + acc1[1] + bz);
                    float hh = acc2[0] + acc2[1] + bn;
                    float n = fast_tanh(xn[s] + r * hh);
                    float hn = (1.f - z) * n + z * hcur;
                    hcur = hn;
                    short hb = f2bf(hn);
                    hbuf[par ^ 1][jj] = hb;
                    hbuf[par ^ 1][160 + jj] = f2bf(hn - bf2f(hb));
                    int t = dir ? (len - 1 - (c * 16 + s)) : (c * 16 + s);
                    out[((size_t)(b * L + t)) * 256 + dir * 128 + jj] = hn;  // fire-and-forget
                }
                par ^= 1;
                bar_lds();  // hbuf[par] ready; single barrier per step; vmcnt untouched
            }
        }
        // rotate prefetched chunk into place (vmcnt wait lands here, a full chunk later)
        if (lane < 16 && c + 1 < nch) {
#pragma unroll
            for (int s = 0; s < 16; s++) { xr[s] = nxr[s]; xz[s] = nxz[s]; xn[s] = nxn[s]; }
        }
    }
}

extern "C" void kernel_launch(void* const* d_in, const int* in_sizes, int n_in,
                              void* d_out, int out_size, void* d_ws, size_t ws_size,
                              hipStream_t stream) {
    const int B = 4, L = 512, D = 256, H = 128;
    const int M = B * L;  // 2048

    const float* v      = (const float*)d_in[0];
    const int* lengths  = (const int*)d_in[1];
    const float* own_W  = (const float*)d_in[3];
    const float* own_b  = (const float*)d_in[4];
    const float* comp_W = (const float*)d_in[5];
    const float* comp_b = (const float*)d_in[6];
    const float* v_attn = (const float*)d_in[7];
    const float* gate_W = (const float*)d_in[8];
    const float* gate_b = (const float*)d_in[9];
    const float* w_ih_f = (const float*)d_in[10];
    const float* w_hh_f = (const float*)d_in[11];
    const float* b_ih_f = (const float*)d_in[12];
    const float* b_hh_f = (const float*)d_in[13];
    const float* w_ih_b = (const float*)d_in[14];
    const float* w_hh_b = (const float*)d_in[15];
    const float* b_ih_b = (const float*)d_in[16];
    const float* b_hh_b = (const float*)d_in[17];

    float* ws   = (float*)d_ws;
    float* own  = ws;                       // [2048,128]
    float* comp = own + (size_t)M * H;      // [2048,128]
    float* inp  = comp + (size_t)M * H;     // [2048,512]
    float* gated = inp + (size_t)M * 512;   // [2048,512]
    float* xp_f = gated + (size_t)M * 512;  // [2048,384]
    float* xp_b = xp_f + (size_t)M * 384;   // [2048,384]
    float* out  = (float*)d_out;            // [2048,256]

    // 1: own & comp projections in one launch (tiles 0..1 -> own, 2..3 -> comp)
    gemm_bias<<<dim3(4, M / 64), 256, 0, stream>>>(
        v, own_W, own_b, own, comp_W, comp_b, comp, lengths, M, H, D, 2, 0);
    // 2: attention (8 q per block) -> inp = [v, C]
    attn_kernel<<<dim3(B * 64), 512, 0, stream>>>(v, lengths, own, comp, v_attn, inp);
    // 3: gate
    gemm_bias<<<dim3(8, M / 64), 256, 0, stream>>>(
        inp, gate_W, gate_b, gated, gate_W, gate_b, gated, lengths, M, 512, 512, 8, 1);
    // 4: input projections for both GRU directions in one launch
    gemm_bias<<<dim3(12, M / 64), 256, 0, stream>>>(
        gated, w_ih_f, b_ih_f, xp_f, w_ih_b, b_ih_b, xp_b, lengths, M, 384, 512, 6, 0);
    // 5: sequential GRU, one block per (dir, batch)
    gru_kernel<<<dim3(8), 512, 0, stream>>>(xp_f, xp_b, w_hh_f, w_hh_b, b_hh_f, b_hh_b, lengths, out);
}

// Round 17
// 354.082 us; speedup vs baseline: 1.5250x; 1.0642x over previous
//
#include <hip/hip_runtime.h>
#include <hip/hip_bf16.h>

#define NEGINF -1e30f

typedef __attribute__((ext_vector_type(8))) short short8;
typedef __attribute__((ext_vector_type(4))) float f32x4;
typedef __attribute__((ext_vector_type(4))) int int4_t;

// Clamp-free: IEEE inf semantics give exact limits (exp->inf => rcp->0), NaN-free.
__device__ __forceinline__ float fast_sigmoid(float x) {
    return __builtin_amdgcn_rcpf(1.f + __expf(-x));
}
__device__ __forceinline__ float fast_tanh(float x) {
    return 1.f - 2.f * __builtin_amdgcn_rcpf(1.f + __expf(2.f * x));
}
// round-to-nearest-even f32 -> bf16 bits
__device__ __forceinline__ short f2bf(float f) {
    unsigned u = __float_as_uint(f);
    return (short)((u + 0x7fff + ((u >> 16) & 1)) >> 16);
}
__device__ __forceinline__ float bf2f(short b) {
    return __uint_as_float(((unsigned)(unsigned short)b) << 16);
}

// LDS-only workgroup barrier (proven R3-R16): waits lgkmcnt only; in-flight global
// loads/stores are NOT drained. Safe when all cross-thread traffic goes through LDS.
__device__ __forceinline__ void bar_lds() {
    asm volatile("s_waitcnt lgkmcnt(0)\n\ts_barrier" ::: "memory");
}

// ---------------- MFMA GEMM (R12, known-good): out = A @ W^T + bias ------------------
__global__ __launch_bounds__(256) void gemm_bias(
    const float* __restrict__ A,
    const float* __restrict__ W1, const float* __restrict__ b1, float* __restrict__ out1,
    const float* __restrict__ W2, const float* __restrict__ b2, float* __restrict__ out2,
    const int* __restrict__ lengths,
    int M, int N, int K, int nsplit, int mode) {
    const int m0 = blockIdx.y * 64;
    if ((m0 & 511) >= lengths[m0 >> 9]) return;  // uniform per block; rows unread
    __shared__ __align__(16) short Abh[2][2048];
    __shared__ __align__(16) short Abl[2][2048];
    __shared__ __align__(16) short Bbh[2][2048];
    __shared__ __align__(16) short Bbl[2][2048];
    const int tid = threadIdx.x;
    int bx = blockIdx.x;
    const float* W = W1; const float* bias = b1; float* out = out1;
    int n0;
    if (bx < nsplit) {
        n0 = bx * 64;
    } else {
        W = W2; bias = b2; out = out2;
        n0 = (bx - nsplit) * 64;
    }
    const int wave = tid >> 6;
    const int lane = tid & 63;
    const int mrow = lane & 15;
    const int quad = lane >> 4;
    const int wm = (wave >> 1) * 32;
    const int wn = (wave & 1) * 32;

    const int r_ = tid >> 2;
    const int sg = (tid & 3) * 8;

    f32x4 acc[2][2];
#pragma unroll
    for (int mt = 0; mt < 2; mt++)
#pragma unroll
        for (int nt = 0; nt < 2; nt++) acc[mt][nt] = (f32x4){0.f, 0.f, 0.f, 0.f};

    float4 a0 = *(const float4*)(A + (size_t)(m0 + r_) * K + sg);
    float4 a1 = *(const float4*)(A + (size_t)(m0 + r_) * K + sg + 4);
    float4 w0 = *(const float4*)(W + (size_t)(n0 + r_) * K + sg);
    float4 w1 = *(const float4*)(W + (size_t)(n0 + r_) * K + sg + 4);

    for (int k0 = 0; k0 < K; k0 += 32) {
        const int cur = (k0 >> 5) & 1;
        {
            float av[8] = {a0.x, a0.y, a0.z, a0.w, a1.x, a1.y, a1.z, a1.w};
            float wv[8] = {w0.x, w0.y, w0.z, w0.w, w1.x, w1.y, w1.z, w1.w};
            short8 ah, al, bh, bl;
#pragma unroll
            for (int j = 0; j < 8; j++) {
                short h = f2bf(av[j]); ah[j] = h; al[j] = f2bf(av[j] - bf2f(h));
                short g = f2bf(wv[j]); bh[j] = g; bl[j] = f2bf(wv[j] - bf2f(g));
            }
            *(short8*)&Abh[cur][r_ * 32 + sg] = ah;
            *(short8*)&Abl[cur][r_ * 32 + sg] = al;
            *(short8*)&Bbh[cur][r_ * 32 + sg] = bh;
            *(short8*)&Bbl[cur][r_ * 32 + sg] = bl;
        }
        if (k0 + 32 < K) {
            a0 = *(const float4*)(A + (size_t)(m0 + r_) * K + k0 + 32 + sg);
            a1 = *(const float4*)(A + (size_t)(m0 + r_) * K + k0 + 32 + sg + 4);
            w0 = *(const float4*)(W + (size_t)(n0 + r_) * K + k0 + 32 + sg);
            w1 = *(const float4*)(W + (size_t)(n0 + r_) * K + k0 + 32 + sg + 4);
        }
        bar_lds();
        short8 Ah[2], Al[2], Bh[2], Bl[2];
#pragma unroll
        for (int t = 0; t < 2; t++) {
            int ar = (wm + t * 16 + mrow) * 32 + quad * 8;
            int br = (wn + t * 16 + mrow) * 32 + quad * 8;
            Ah[t] = *(const short8*)&Abh[cur][ar];
            Al[t] = *(const short8*)&Abl[cur][ar];
            Bh[t] = *(const short8*)&Bbh[cur][br];
            Bl[t] = *(const short8*)&Bbl[cur][br];
        }
#pragma unroll
        for (int mt = 0; mt < 2; mt++)
#pragma unroll
            for (int nt = 0; nt < 2; nt++) {
                acc[mt][nt] = __builtin_amdgcn_mfma_f32_16x16x32_bf16(Ah[mt], Bh[nt], acc[mt][nt], 0, 0, 0);
                acc[mt][nt] = __builtin_amdgcn_mfma_f32_16x16x32_bf16(Al[mt], Bh[nt], acc[mt][nt], 0, 0, 0);
                acc[mt][nt] = __builtin_amdgcn_mfma_f32_16x16x32_bf16(Ah[mt], Bl[nt], acc[mt][nt], 0, 0, 0);
            }
        bar_lds();
    }
    float bsv[2];
#pragma unroll
    for (int nt = 0; nt < 2; nt++) bsv[nt] = bias[n0 + wn + nt * 16 + mrow];
#pragma unroll
    for (int mt = 0; mt < 2; mt++)
#pragma unroll
        for (int nt = 0; nt < 2; nt++) {
            int n = n0 + wn + nt * 16 + mrow;
#pragma unroll
            for (int r = 0; r < 4; r++) {
                int m = m0 + wm + mt * 16 + quad * 4 + r;
                float val = acc[mt][nt][r] + bsv[nt];
                if (mode == 1) val = fast_sigmoid(val) * A[(size_t)m * K + n];
                out[(size_t)m * N + n] = val;
            }
        }
}

// ---------------- Attention, 8 queries per block (R12, known-good) -------------------
__global__ __launch_bounds__(512) void attn_kernel(
    const float* __restrict__ v, const int* __restrict__ lengths,
    const float* __restrict__ own, const float* __restrict__ comp,
    const float* __restrict__ v_attn, float* __restrict__ inp) {
    const int L = 512, D = 256, H = 128;
    const int b = blockIdx.x >> 6;
    const int q0 = (blockIdx.x & 63) * 8;
    const int len = lengths[b];
    if (q0 >= len) return;
    const int tid = threadIdx.x;
    const float K2E = 2.8853900817779268f;  // 2*log2(e)
    __shared__ __align__(16) float oKT[128 * 8];
    __shared__ float va2s[128];
    __shared__ __align__(16) float scf[512 * 12];
    __shared__ float inv8[8];

    for (int i = tid; i < 1024; i += 512) {
        int qq = i >> 7, hh = i & 127;
        oKT[hh * 8 + qq] = K2E * own[((size_t)(b * L + q0 + qq)) * H + hh];
    }
    if (tid < 128) va2s[tid] = -2.f * v_attn[tid];
    __syncthreads();

    {
        const int k = tid;
        float acc[8];
#pragma unroll
        for (int q = 0; q < 8; q++) acc[q] = 0.f;
        if (k < len) {
            const float* cp = comp + ((size_t)(b * L + k)) * H;
            for (int h = 0; h < 128; h += 4) {
                float4 c4 = *(const float4*)(cp + h);
                const float* cv = (const float*)&c4;
#pragma unroll
                for (int j = 0; j < 4; j++) {
                    float cK = cv[j] * K2E;
                    float va = va2s[h + j];
                    float4 o0 = *(const float4*)&oKT[(h + j) * 8];
                    float4 o1 = *(const float4*)&oKT[(h + j) * 8 + 4];
                    const float* op0 = (const float*)&o0;
                    const float* op1 = (const float*)&o1;
#pragma unroll
                    for (int q = 0; q < 4; q++) {
                        float r = __builtin_amdgcn_rcpf(1.f + exp2f(cK + op0[q]));
                        acc[q] = fmaf(va, r, acc[q]);
                    }
#pragma unroll
                    for (int q = 0; q < 4; q++) {
                        float r = __builtin_amdgcn_rcpf(1.f + exp2f(cK + op1[q]));
                        acc[4 + q] = fmaf(va, r, acc[4 + q]);
                    }
                }
            }
#pragma unroll
            for (int q = 0; q < 8; q++) acc[q] = __expf(acc[q]);  // bounded, no max pass
        }
        *(float4*)&scf[k * 12] = *(float4*)&acc[0];
        *(float4*)&scf[k * 12 + 4] = *(float4*)&acc[4];
    }
    __syncthreads();

    {
        int w = tid >> 6, l = tid & 63;
        float s = 0.f;
#pragma unroll
        for (int kk = 0; kk < 8; kk++) s += scf[(l + kk * 64) * 12 + w];
#pragma unroll
        for (int off = 1; off < 64; off <<= 1) s += __shfl_xor(s, off);
        if (l == 0) inv8[w] = __builtin_amdgcn_rcpf(s);
    }
    __syncthreads();

    {
        const int d = tid & 255;
        const int qh = tid >> 8;
        float c0 = 0.f, c1 = 0.f, c2 = 0.f, c3 = 0.f;
        const float* vb = v + ((size_t)b * L) * D + d;
        for (int k = 0; k < L; k += 2) {
            float v0 = vb[(size_t)k * D];
            float v1 = vb[(size_t)(k + 1) * D];
            float4 s0 = *(const float4*)&scf[k * 12 + qh * 4];
            float4 s1 = *(const float4*)&scf[(k + 1) * 12 + qh * 4];
            c0 += s0.x * v0 + s1.x * v1;
            c1 += s0.y * v0 + s1.y * v1;
            c2 += s0.z * v0 + s1.z * v1;
            c3 += s0.w * v0 + s1.w * v1;
        }
        float cc[4] = {c0, c1, c2, c3};
#pragma unroll
        for (int j = 0; j < 4; j++) {
            int q = q0 + qh * 4 + j;
            size_t row = ((size_t)(b * L + q)) * 512;
            inp[row + 256 + d] = cc[j] * inv8[qh * 4 + j];
            inp[row + d] = v[((size_t)(b * L + q)) * D + d];
        }
    }
}

// ---------------- GRU recurrence: i8 MFMA K=64 (halved matvec cost) ------------------
// R16 structure (hbuf-only step loop, register xp chunks, fire-and-forget out, g-major)
// with the matvec moved to mfma_i32_16x16x64_i8: 6 MFMA/wave/step (was 12), 2-chains.
// h: |h| < 1 strictly -> Q0.13 fixed point h13 = hi*64 + lo (two i8 A-rows; integer
// dot is EXACT). W_hh: per-row i8 + row scale (rel err 2^-8 ~ the validated bf16-W).
// i32 accumulation exact (max |sum| ~2M << 2^31). Dequant: one fma per gate with the
// lane-local row scale (gate lane's mrow == its gate dim). A/B pack bytes with the
// same (quad,j)->k order -> any HW k-permutation cancels; C mapping dtype-independent.
// hbuf: hi at byte 0, lo at byte 192 (word 48 === 16 mod 32): hi/lo readers hit
// disjoint 16-bank halves for both K-tiles.
__global__ __launch_bounds__(512, 1) void gru_kernel(
    const float* __restrict__ xp_f, const float* __restrict__ xp_b,
    const float* __restrict__ w_hh_f, const float* __restrict__ w_hh_b,
    const float* __restrict__ b_hh_f, const float* __restrict__ b_hh_b,
    const int* __restrict__ lengths, float* __restrict__ out) {
    const int L = 512, H = 128;
    const int dir = blockIdx.x >> 2;
    const int b = blockIdx.x & 3;
    const float* xp = dir ? xp_b : xp_f;
    const float* w_hh = dir ? w_hh_b : w_hh_f;
    const float* b_hh = dir ? b_hh_b : b_hh_f;
    const int tid = threadIdx.x;
    const int wave = tid >> 6;
    const int lane = tid & 63;
    const int mrow = lane & 15;
    const int quad = lane >> 4;
    const int jj = 16 * wave + lane;  // gate dim for lanes lane<16

    // [parity][ h_hi bytes 0..127 | pad | h_lo bytes 192..319 | pad..383 ]
    __shared__ __align__(16) signed char hbufc[2][384];

    // ---- W_hh -> per-row i8 + scale. Lane (mrow,quad) holds B[k=kt*64+quad*16+j][row]
    // for rows g*128 + 16*wave + mrow; row max reduced across the 4 quads via shfl. ----
    int4_t wb[3][2];
    float ws[3];  // dequant scale (row_scale / 8192) — meaningful for gate lanes
#pragma unroll
    for (int g = 0; g < 3; g++) {
        int row = g * 128 + 16 * wave + mrow;
        float wv[32];
#pragma unroll
        for (int kt = 0; kt < 2; kt++)
#pragma unroll
            for (int j4 = 0; j4 < 4; j4++) {
                float4 f4 = *(const float4*)(w_hh + (size_t)row * H + kt * 64 + quad * 16 + j4 * 4);
                wv[kt * 16 + j4 * 4 + 0] = f4.x;
                wv[kt * 16 + j4 * 4 + 1] = f4.y;
                wv[kt * 16 + j4 * 4 + 2] = f4.z;
                wv[kt * 16 + j4 * 4 + 3] = f4.w;
            }
        float mx = 0.f;
#pragma unroll
        for (int j = 0; j < 32; j++) mx = fmaxf(mx, fabsf(wv[j]));
        mx = fmaxf(mx, __shfl_xor(mx, 16));
        mx = fmaxf(mx, __shfl_xor(mx, 32));
        mx = fmaxf(mx, 1e-30f);
        float inv_s = 127.f / mx;
        ws[g] = (mx / 127.f) * (1.f / 8192.f);
#pragma unroll
        for (int kt = 0; kt < 2; kt++) {
            int tmp[4] = {0, 0, 0, 0};
#pragma unroll
            for (int j = 0; j < 16; j++) {
                int q = (int)rintf(wv[kt * 16 + j] * inv_s);
                tmp[j >> 2] |= (q & 0xff) << ((j & 3) * 8);
            }
            wb[g][kt] = (int4_t){tmp[0], tmp[1], tmp[2], tmp[3]};
        }
    }
    float br = 0.f, bz = 0.f, bn = 0.f, hcur = 0.f;
    if (lane < 16) {
        br = b_hh[jj];
        bz = b_hh[128 + jj];
        bn = b_hh[256 + jj];
    }

    const int len = lengths[b];
    // pre-zero masked tail: out[b, t, dir*128+k] = 0 for t in [len, L)
    for (int i = tid; i < (L - len) * 128; i += 512) {
        int tt = len + (i >> 7);
        int kk = i & 127;
        out[((size_t)(b * L + tt)) * 256 + dir * 128 + kk] = 0.f;
    }
    for (int i = tid; i < 768; i += 512) ((signed char*)hbufc)[i] = 0;

    const int nch = (len + 15) >> 4;
    // gate-lane xp registers for the current chunk (fully unrolled => stays in VGPRs)
    float xr[16], xz[16], xn[16];
    if (lane < 16) {
#pragma unroll
        for (int s = 0; s < 16; s++) {
            if (s < len) {
                int t = dir ? (len - 1 - s) : s;
                size_t base = ((size_t)(b * L + t)) * 384;
                xr[s] = xp[base + jj];
                xz[s] = xp[base + 128 + jj];
                xn[s] = xp[base + 256 + jj];
            }
        }
    }
    __syncthreads();

    // A-frag byte base: row0 (h_hi) at 0, row1 (h_lo) at 192; rows 2-15 duplicates
    const int bbase = ((mrow & 1) ? 192 : 0) + quad * 16;
    int par = 0;

    for (int c = 0; c < nch; c++) {
        const int cnt = min(16, len - c * 16);
        // prefetch chunk c+1 into a second register set; drains over this chunk
        float nxr[16], nxz[16], nxn[16];
        if (lane < 16 && c + 1 < nch) {
#pragma unroll
            for (int s = 0; s < 16; s++) {
                int rr = (c + 1) * 16 + s;
                if (rr < len) {
                    int t = dir ? (len - 1 - rr) : rr;
                    size_t base = ((size_t)(b * L + t)) * 384;
                    nxr[s] = xp[base + jj];
                    nxz[s] = xp[base + 128 + jj];
                    nxn[s] = xp[base + 256 + jj];
                }
            }
        }
#pragma unroll
        for (int s = 0; s < 16; s++) {
            if (s < cnt) {  // cnt uniform per block -> barrier counts match
                int4_t af0 = *(const int4_t*)&hbufc[par][bbase];
                int4_t af1 = *(const int4_t*)&hbufc[par][bbase + 64];
                int4_t a0 = (int4_t){0, 0, 0, 0};
                int4_t a1 = (int4_t){0, 0, 0, 0};
                int4_t a2 = (int4_t){0, 0, 0, 0};
                // g-major: a0 (r) complete after 2, a1 (z) after 4, a2 (n) last
                a0 = __builtin_amdgcn_mfma_i32_16x16x64_i8(af0, wb[0][0], a0, 0, 0, 0);
                a0 = __builtin_amdgcn_mfma_i32_16x16x64_i8(af1, wb[0][1], a0, 0, 0, 0);
                a1 = __builtin_amdgcn_mfma_i32_16x16x64_i8(af0, wb[1][0], a1, 0, 0, 0);
                a1 = __builtin_amdgcn_mfma_i32_16x16x64_i8(af1, wb[1][1], a1, 0, 0, 0);
                a2 = __builtin_amdgcn_mfma_i32_16x16x64_i8(af0, wb[2][0], a2, 0, 0, 0);
                a2 = __builtin_amdgcn_mfma_i32_16x16x64_i8(af1, wb[2][1], a2, 0, 0, 0);
                if (lane < 16) {
                    // C rows 0/1 (regs 0/1) = W.h_hi / W.h_lo integer dots; h13 = hi*64+lo
                    float r = fast_sigmoid(fmaf((float)(a0[0] * 64 + a0[1]), ws[0], xr[s] + br));
                    float z = fast_sigmoid(fmaf((float)(a1[0] * 64 + a1[1]), ws[1], xz[s] + bz));
                    float hh = fmaf((float)(a2[0] * 64 + a2[1]), ws[2], bn);
                    float n = fast_tanh(xn[s] + r * hh);
                    float hn = (1.f - z) * n + z * hcur;
                    hcur = hn;
                    // quantize h -> Q0.13 hi/lo (|h| < 1; clamp guards rint to 8192)
                    float hs = fminf(fmaxf(hn * 8192.f, -8191.f), 8191.f);
                    int h13 = (int)rintf(hs);
                    int hi = h13 >> 6;             // arithmetic shift (floor)
                    int lo = h13 - (hi << 6);      // in [0, 63]
                    hbufc[par ^ 1][jj] = (signed char)hi;
                    hbufc[par ^ 1][192 + jj] = (signed char)lo;
                    int t = dir ? (len - 1 - (c * 16 + s)) : (c * 16 + s);
                    out[((size_t)(b * L + t)) * 256 + dir * 128 + jj] = hn;  // fire-and-forget
                }
                par ^= 1;
                bar_lds();  // hbufc[par] ready; single barrier per step; vmcnt untouched
            }
        }
        // rotate prefetched chunk into place (vmcnt wait lands here, a full chunk later)
        if (lane < 16 && c + 1 < nch) {
#pragma unroll
            for (int s = 0; s < 16; s++) { xr[s] = nxr[s]; xz[s] = nxz[s]; xn[s] = nxn[s]; }
        }
    }
}

extern "C" void kernel_launch(void* const* d_in, const int* in_sizes, int n_in,
                              void* d_out, int out_size, void* d_ws, size_t ws_size,
                              hipStream_t stream) {
    const int B = 4, L = 512, D = 256, H = 128;
    const int M = B * L;  // 2048

    const float* v      = (const float*)d_in[0];
    const int* lengths  = (const int*)d_in[1];
    const float* own_W  = (const float*)d_in[3];
    const float* own_b  = (const float*)d_in[4];
    const float* comp_W = (const float*)d_in[5];
    const float* comp_b = (const float*)d_in[6];
    const float* v_attn = (const float*)d_in[7];
    const float* gate_W = (const float*)d_in[8];
    const float* gate_b = (const float*)d_in[9];
    const float* w_ih_f = (const float*)d_in[10];
    const float* w_hh_f = (const float*)d_in[11];
    const float* b_ih_f = (const float*)d_in[12];
    const float* b_hh_f = (const float*)d_in[13];
    const float* w_ih_b = (const float*)d_in[14];
    const float* w_hh_b = (const float*)d_in[15];
    const float* b_ih_b = (const float*)d_in[16];
    const float* b_hh_b = (const float*)d_in[17];

    float* ws   = (float*)d_ws;
    float* own  = ws;                       // [2048,128]
    float* comp = own + (size_t)M * H;      // [2048,128]
    float* inp  = comp + (size_t)M * H;     // [2048,512]
    float* gated = inp + (size_t)M * 512;   // [2048,512]
    float* xp_f = gated + (size_t)M * 512;  // [2048,384]
    float* xp_b = xp_f + (size_t)M * 384;   // [2048,384]
    float* out  = (float*)d_out;            // [2048,256]

    // 1: own & comp projections in one launch (tiles 0..1 -> own, 2..3 -> comp)
    gemm_bias<<<dim3(4, M / 64), 256, 0, stream>>>(
        v, own_W, own_b, own, comp_W, comp_b, comp, lengths, M, H, D, 2, 0);
    // 2: attention (8 q per block) -> inp = [v, C]
    attn_kernel<<<dim3(B * 64), 512, 0, stream>>>(v, lengths, own, comp, v_attn, inp);
    // 3: gate
    gemm_bias<<<dim3(8, M / 64), 256, 0, stream>>>(
        inp, gate_W, gate_b, gated, gate_W, gate_b, gated, lengths, M, 512, 512, 8, 1);
    // 4: input projections for both GRU directions in one launch
    gemm_bias<<<dim3(12, M / 64), 256, 0, stream>>>(
        gated, w_ih_f, b_ih_f, xp_f, w_ih_b, b_ih_b, xp_b, lengths, M, 384, 512, 6, 0);
    // 5: sequential GRU, one block per (dir, batch)
    gru_kernel<<<dim3(8), 512, 0, stream>>>(xp_f, xp_b, w_hh_f, w_hh_b, b_hh_f, b_hh_b, lengths, out);
}